// Round 10
// baseline (332.831 us; speedup 1.0000x reference)
//
#include <hip/hip_runtime.h>
#include <hip/hip_bf16.h>

// SwitchLinear: B=4,S=2048,D_IN=1024,D_OUT=1024,E=8
// Established contract: ALL inputs fp32, OUTPUT fp32 (out_size=8388609 floats:
// 8192x1024 dense out + aux scalar). ws >= 262400 B. Routing = argmax of fp32
// gate logits; out[t,:] = x[t]@We[top1]^T + be[top1]; aux = mean((mean_gate*E)^2).
// Value GEMM: bf16 MFMA (~1e-3 error << 6.4e-2 threshold). Gate logits fp32.
//
// v11: maximum-TLP gate. r9 counters: gate occupancy 7.7% (4 waves/CU),
// VALUBusy 4.2%, x L3-resident -> pure latency starvation; every prior gate
// had <=10 waves/CU + serial barriers. Now: ONE WAVE PER TOKEN, 2048 blocks
// x 256 thr (8192 waves, no barriers in hot path, no LDS in compute).
// Lane loads x at lane*4+{0,256,512,768} (4x coalesced b128); per expert 4
// b128 of Wg (L1-hit, unroll 2) + 16 fmaf -> 8 indep chains. 8-acc butterfly
// reduce (10 shuffles/token vs 48). Records = 2048 x 4 tokens (64B each);
// v9's verified last-block route, re-laned 256thr x 8recs.
// gemm = v7 verbatim (76us, 0 bank conflicts).

#define NTOK 8192
#define DIN  1024
#define DOUT 1024
#define NE   8

typedef unsigned short u16;
typedef unsigned int   u32;
typedef unsigned long long u64;
typedef short  bf16x8 __attribute__((ext_vector_type(8)));
typedef float  f32x4  __attribute__((ext_vector_type(4)));

__device__ __forceinline__ u16 f2bf(float f) {
    __hip_bfloat16 h = __float2bfloat16(f);   // RNE
    return *(u16*)&h;
}

// ws layout: [0,32) counts[8] | [32,36) done | [256, 262400) tok_list[8][8192]
// First 128KB of tok_list region doubles as record staging (2048 x 64B);
// route preloads its records before the scatter overwrites them.

// ---------------------------------------------------------------------------
// gate+route: 2048 blocks x 256 thr; wave = 1 token; block = 4 tokens = 1 rec.
// ---------------------------------------------------------------------------
__global__ __launch_bounds__(256) void gate_route_kernel(
    const float* __restrict__ x, const float* __restrict__ Wg,
    const float* __restrict__ bg, int* __restrict__ counts,
    int* __restrict__ done, int* __restrict__ tok_list,
    u32* __restrict__ stage, float* __restrict__ out)
{
    __shared__ union {
        struct { int am[4]; float mg[4][NE]; } g;
        struct { int cnt[256][9]; float mgred[4][NE]; } r;   // 9.3 KB
    } sm;
    __shared__ int isLast;

    const int tid  = threadIdx.x;
    const int bid  = blockIdx.x;
    const int wave = tid >> 6;
    const int lane = tid & 63;

    // ------------------------------ gate -----------------------------------
    {
        const int t = bid * 4 + wave;
        const float* xr = x + (size_t)t * DIN + lane * 4;

        f32x4 xv0 = *(const f32x4*)(xr);
        f32x4 xv1 = *(const f32x4*)(xr + 256);
        f32x4 xv2 = *(const f32x4*)(xr + 512);
        f32x4 xv3 = *(const f32x4*)(xr + 768);

        float acc[NE];
        #pragma unroll 2
        for (int e = 0; e < NE; ++e) {
            const float* wr = Wg + e * DIN + lane * 4;
            f32x4 w0 = *(const f32x4*)(wr);
            f32x4 w1 = *(const f32x4*)(wr + 256);
            f32x4 w2 = *(const f32x4*)(wr + 512);
            f32x4 w3 = *(const f32x4*)(wr + 768);
            float a = 0.f;
            #pragma unroll
            for (int q = 0; q < 4; ++q) a = fmaf(w0[q], xv0[q], a);
            #pragma unroll
            for (int q = 0; q < 4; ++q) a = fmaf(w1[q], xv1[q], a);
            #pragma unroll
            for (int q = 0; q < 4; ++q) a = fmaf(w2[q], xv2[q], a);
            #pragma unroll
            for (int q = 0; q < 4; ++q) a = fmaf(w3[q], xv3[q], a);
            acc[e] = a;
        }

        // 8-acc butterfly: fold expert halves while halving lane redundancy.
        // After off=4,2,1: lane l holds full-group partial for expert (l&7).
        float r4[4], r2[2], rr;
        #pragma unroll
        for (int i = 0; i < 4; ++i) {
            float own  = (lane & 4) ? acc[i + 4] : acc[i];
            float send = (lane & 4) ? acc[i]     : acc[i + 4];
            r4[i] = own + __shfl_xor(send, 4, 64);
        }
        #pragma unroll
        for (int i = 0; i < 2; ++i) {
            float own  = (lane & 2) ? r4[i + 2] : r4[i];
            float send = (lane & 2) ? r4[i]     : r4[i + 2];
            r2[i] = own + __shfl_xor(send, 2, 64);
        }
        {
            float own  = (lane & 1) ? r2[1] : r2[0];
            float send = (lane & 1) ? r2[0] : r2[1];
            rr = own + __shfl_xor(send, 1, 64);
        }
        rr += __shfl_xor(rr, 8, 64);
        rr += __shfl_xor(rr, 16, 64);
        rr += __shfl_xor(rr, 32, 64);

        const int e = lane & 7;
        const float logit = rr + bg[e];

        // 8-lane argmax tree, first-max-wins (== np linear scan)
        float v = logit; int ix = e;
        #pragma unroll
        for (int off = 1; off < 8; off <<= 1) {
            float pv = __shfl_xor(v, off, 64);
            int  pix = __shfl_xor(ix, off, 64);
            if (pv > v || (pv == v && pix < ix)) { v = pv; ix = pix; }
        }

        float p = __expf(logit - v);
        float ssum = p;
        #pragma unroll
        for (int off = 1; off < 8; off <<= 1) ssum += __shfl_xor(ssum, off, 64);
        const float mgval = p * (1.f / ssum);

        if (lane == 0) sm.g.am[wave] = ix;
        if (lane < NE) sm.g.mg[wave][lane] = mgval;
        __syncthreads();

        u32* rec = stage + (size_t)bid * 16;
        if (tid == 0) {
            u32 pack = (u32)sm.g.am[0] | ((u32)sm.g.am[1] << 4)
                     | ((u32)sm.g.am[2] << 8) | ((u32)sm.g.am[3] << 12);
            rec[0] = pack;
        }
        if (tid < NE)
            rec[2 + tid] = __float_as_uint(sm.g.mg[0][tid] + sm.g.mg[1][tid]
                                         + sm.g.mg[2][tid] + sm.g.mg[3][tid]);
    }

    // ---------------- last-block election (device-scope) -------------------
    __threadfence();
    __syncthreads();
    if (tid == 0) {
        int old = __hip_atomic_fetch_add(done, 1, __ATOMIC_ACQ_REL,
                                         __HIP_MEMORY_SCOPE_AGENT);
        isLast = (old == 2047);
    }
    __syncthreads();
    if (!isLast) return;
    __threadfence();

    // ---------------- route (elected block, 256 thr, 8 recs/thr) -----------
    {
        u32 pk[8];
        float mgr[NE];
        #pragma unroll
        for (int q = 0; q < NE; ++q) mgr[q] = 0.f;
        #pragma unroll
        for (int j = 0; j < 8; ++j) {
            const u32* rec = stage + (size_t)(8 * tid + j) * 16;
            pk[j] = rec[0];
            #pragma unroll
            for (int q = 0; q < NE; ++q) mgr[q] += __uint_as_float(rec[2 + q]);
        }
        __syncthreads();    // all record loads done before union overwrite

        // per-thread aggregate counts over its 8 records (32 tokens)
        {
            int c8[NE];
            #pragma unroll
            for (int q = 0; q < NE; ++q) c8[q] = 0;
            #pragma unroll
            for (int j = 0; j < 8; ++j)
                #pragma unroll
                for (int it = 0; it < 4; ++it)
                    c8[(int)((pk[j] >> (4 * it)) & 7)]++;
            #pragma unroll
            for (int q = 0; q < NE; ++q) sm.r.cnt[tid][q] = c8[q];
        }
        __syncthreads();

        // exclusive scan over 256 thread-aggregates; wave w: experts 2w,2w+1
        #pragma unroll
        for (int half = 0; half < 2; ++half) {
            const int ee = wave * 2 + half;
            int carry = 0;
            #pragma unroll 1
            for (int chn = 0; chn < 4; ++chn) {
                int vv = sm.r.cnt[chn * 64 + lane][ee];
                int incl = vv;
                #pragma unroll
                for (int off = 1; off < 64; off <<= 1) {
                    int nn = __shfl_up(incl, off, 64);
                    if (lane >= off) incl += nn;
                }
                sm.r.cnt[chn * 64 + lane][ee] = incl - vv + carry;
                carry += __shfl(incl, 63, 64);
            }
            if (lane == 0) counts[ee] = carry;
        }
        __syncthreads();

        // scatter: thread-local bases, tokens in ascending order
        {
            int base[NE];
            #pragma unroll
            for (int q = 0; q < NE; ++q) base[q] = sm.r.cnt[tid][q];
            #pragma unroll
            for (int j = 0; j < 8; ++j) {
                #pragma unroll
                for (int it = 0; it < 4; ++it) {
                    int e3 = (int)((pk[j] >> (4 * it)) & 7);
                    tok_list[e3 * NTOK + base[e3]++] = (8 * tid + j) * 4 + it;
                }
            }
        }

        // mean-gate totals + aux
        #pragma unroll
        for (int q = 0; q < NE; ++q)
            #pragma unroll
            for (int off = 32; off > 0; off >>= 1)
                mgr[q] += __shfl_xor(mgr[q], off, 64);
        if (lane == 0)
            #pragma unroll
            for (int q = 0; q < NE; ++q) sm.r.mgred[wave][q] = mgr[q];
        __syncthreads();
        if (tid == 0) {
            float s = 0.f;
            #pragma unroll
            for (int q = 0; q < NE; ++q) {
                float m = (sm.r.mgred[0][q] + sm.r.mgred[1][q]
                         + sm.r.mgred[2][q] + sm.r.mgred[3][q]) * (8.0f / 8192.0f);
                s += m * m;
            }
            out[(size_t)NTOK * DOUT] = s * 0.125f;
        }
    }
}

// ---------------------------------------------------------------------------
// grouped GEMM (v7 verbatim, verified 76us / 0 bank conflicts):
// 64x128 tile, BK=64, 4 waves each 64x32 (4x2 of 16x16x32).
// LDS: bf16 sA[64][64] (8KB) + sB[128][64] (16KB), single-buffered.
// XOR-swizzled chunks (cx = ch ^ (row&7); rows 128B) on write and read.
// Schedule: barrier / write(k) / issue loads(k+1) / barrier / compute(k).
// Grid dim3(8 n, 128 m, 8 e): ~1088 active blocks = 4.25/CU.
// ---------------------------------------------------------------------------
__global__ __launch_bounds__(256) void moe_gemm(
    const float* __restrict__ x, const float* __restrict__ We,
    const float* __restrict__ be, const int* __restrict__ counts,
    const int* __restrict__ tok_list, float* __restrict__ out)
{
    const int e   = blockIdx.z;
    const int cnt = counts[e];
    const int m0  = blockIdx.y * 64;
    if (m0 >= cnt) return;
    const int n0  = blockIdx.x * 128;

    __shared__ u16 sA[64 * 64];    // 8 KB
    __shared__ u16 sB[128 * 64];   // 16 KB
    __shared__ int toks[64];

    const int tid = threadIdx.x;
    if (tid < 64) {
        int gr = m0 + tid;
        toks[tid] = (gr < cnt) ? tok_list[e * NTOK + gr] : tok_list[e * NTOK];
    }
    __syncthreads();

    const int lane = tid & 63;
    const int wave = tid >> 6;
    const int wn   = wave * 32;
    const int lrow = lane & 15;
    const int quad = lane >> 4;
    const int l7   = lrow & 7;

    f32x4 acc[4][2];
    #pragma unroll
    for (int i = 0; i < 4; ++i)
        #pragma unroll
        for (int j = 0; j < 2; ++j) acc[i][j] = (f32x4){0.f, 0.f, 0.f, 0.f};

    const int srow = tid >> 3;
    const int ch   = tid & 7;
    const int cx   = ch ^ (srow & 7);

    const float* aS[2];
    const float* bS[4];
    #pragma unroll
    for (int s = 0; s < 2; ++s)
        aS[s] = x + (size_t)toks[srow + 32 * s] * DIN + ch * 8;
    #pragma unroll
    for (int s = 0; s < 4; ++s)
        bS[s] = We + ((size_t)e << 20) + ((size_t)(n0 + srow + 32 * s) << 10) + ch * 8;

    f32x4 ar[2][2], br[4][2];

    #define LOADR(k0)                                            \
        do {                                                     \
            _Pragma("unroll")                                    \
            for (int s = 0; s < 2; ++s) {                        \
                ar[s][0] = *(const f32x4*)(aS[s] + (k0));        \
                ar[s][1] = *(const f32x4*)(aS[s] + (k0) + 4);    \
            }                                                    \
            _Pragma("unroll")                                    \
            for (int s = 0; s < 4; ++s) {                        \
                br[s][0] = *(const f32x4*)(bS[s] + (k0));        \
                br[s][1] = *(const f32x4*)(bS[s] + (k0) + 4);    \
            }                                                    \
        } while (0)

    #define STOREW()                                                     \
        do {                                                             \
            _Pragma("unroll")                                            \
            for (int s = 0; s < 2; ++s) {                                \
                union { u16 h[8]; uint4 u; } ua;                         \
                _Pragma("unroll")                                        \
                for (int q = 0; q < 4; ++q) {                            \
                    ua.h[q]     = f2bf(ar[s][0][q]);                     \
                    ua.h[4 + q] = f2bf(ar[s][1][q]);                     \
                }                                                        \
                *(uint4*)&sA[(srow + 32 * s) * 64 + cx * 8] = ua.u;      \
            }                                                            \
            _Pragma("unroll")                                            \
            for (int s = 0; s < 4; ++s) {                                \
                union { u16 h[8]; uint4 u; } ub;                         \
                _Pragma("unroll")                                        \
                for (int q = 0; q < 4; ++q) {                            \
                    ub.h[q]     = f2bf(br[s][0][q]);                     \
                    ub.h[4 + q] = f2bf(br[s][1][q]);                     \
                }                                                        \
                *(uint4*)&sB[(srow + 32 * s) * 64 + cx * 8] = ub.u;      \
            }                                                            \
        } while (0)

    #define COMPUTE()                                                         \
        do {                                                                  \
            bf16x8 af[2][4], bv[2][2];                                        \
            _Pragma("unroll")                                                 \
            for (int ks = 0; ks < 2; ++ks) {                                  \
                const int so = ((ks * 4 + quad) ^ l7) * 8;                    \
                _Pragma("unroll")                                             \
                for (int i = 0; i < 4; ++i)                                   \
                    af[ks][i] = *(const bf16x8*)&sA[(i * 16 + lrow) * 64 + so]; \
                _Pragma("unroll")                                             \
                for (int j = 0; j < 2; ++j)                                   \
                    bv[ks][j] = *(const bf16x8*)&sB[(wn + j * 16 + lrow) * 64 + so]; \
            }                                                                 \
            _Pragma("unroll")                                                 \
            for (int ks = 0; ks < 2; ++ks)                                    \
                _Pragma("unroll")                                             \
                for (int i = 0; i < 4; ++i)                                   \
                    _Pragma("unroll")                                         \
                    for (int j = 0; j < 2; ++j)                               \
                        acc[i][j] = __builtin_amdgcn_mfma_f32_16x16x32_bf16(  \
                            af[ks][i], bv[ks][j], acc[i][j], 0, 0, 0);        \
        } while (0)

    LOADR(0);
    #pragma unroll 1
    for (int k0 = 0; k0 < DIN; k0 += 64) {
        __syncthreads();
        STOREW();
        if (k0 + 64 < DIN) LOADR(k0 + 64);
        __syncthreads();
        COMPUTE();
    }

    #undef LOADR
    #undef STOREW
    #undef COMPUTE

    #pragma unroll
    for (int j = 0; j < 2; ++j) {
        const int col = n0 + wn + j * 16 + lrow;
        const float bev = be[e * DOUT + col];
        #pragma unroll
        for (int i = 0; i < 4; ++i) {
            #pragma unroll
            for (int r = 0; r < 4; ++r) {
                const int rl = i * 16 + quad * 4 + r;
                if (m0 + rl < cnt) {
                    const int tok = toks[rl];
                    out[((size_t)tok << 10) + col] = acc[i][j][r] + bev;
                }
            }
        }
    }
}

extern "C" void kernel_launch(void* const* d_in, const int* in_sizes, int n_in,
                              void* d_out, int out_size, void* d_ws, size_t ws_size,
                              hipStream_t stream) {
    const float* x  = (const float*)d_in[0];
    const float* We = (const float*)d_in[1];
    const float* be = (const float*)d_in[2];
    const float* Wg = (const float*)d_in[3];
    const float* bg = (const float*)d_in[4];
    float* out = (float*)d_out;

    int* counts   = (int*)d_ws;
    int* done     = (int*)((char*)d_ws + 32);
    int* tok_list = (int*)((char*)d_ws + 256);
    u32* stage    = (u32*)((char*)d_ws + 256);

    hipMemsetAsync(d_ws, 0, 64, stream);   // zero counts + done ticket
    gate_route_kernel<<<2048, 256, 0, stream>>>(x, Wg, bg, counts, done,
                                                tok_list, stage, out);
    moe_gemm<<<dim3(8, 128, 8), 256, 0, stream>>>(x, We, be, counts, tok_list, out);
}

// Round 11
// 204.412 us; speedup vs baseline: 1.6282x; 1.6282x over previous
//
#include <hip/hip_runtime.h>
#include <hip/hip_bf16.h>

// SwitchLinear: B=4,S=2048,D_IN=1024,D_OUT=1024,E=8
// Established contract: ALL inputs fp32, OUTPUT fp32 (out_size=8388609 floats:
// 8192x1024 dense out + aux scalar). ws >= 262400 B. Routing = argmax of fp32
// gate logits; out[t,:] = x[t]@We[top1]^T + be[top1]; aux = mean((mean_gate*E)^2).
// Value GEMM: bf16 MFMA (~1e-3 error << 6.4e-2 threshold). Gate logits fp32.
//
// v12 = round-6 champion (182us: gemm 76 + gate/route ~25 + ~80 harness gap)
// with ONE change: gemm K-SPLIT x2. Each (m,n,e) tile computed by two blocks
// (K=0..512 and 512..1024) -> 2x live blocks (TLP hides the exposed ~300cyc
// load->store gap) with ZERO extra L2 read traffic. Epilogue: hardware fp32
// atomics (unsafeAtomicAdd -> global_atomic_add_f32; 2 commutative addends =
// bit-deterministic; verification memsets out before the checked run). Bias
// added by kb==0 block only.
// Lessons carried: v9-v11 gate rewrites chased a ghost (accounting error);
// v11's 2048 same-address done-tickets serialized at ~80ns = 164us.
// gate/route = round-6 verbatim (v3 zero-atomic records + 1-block scan).

#define NTOK 8192
#define DIN  1024
#define DOUT 1024
#define NE   8

typedef unsigned short u16;
typedef unsigned int   u32;
typedef unsigned long long u64;
typedef short  bf16x8 __attribute__((ext_vector_type(8)));
typedef float  f32x4  __attribute__((ext_vector_type(4)));

__device__ __forceinline__ u16 f2bf(float f) {
    __hip_bfloat16 h = __float2bfloat16(f);   // RNE
    return *(u16*)&h;
}

// ws layout: [0,32) counts[8] | [256, 262400) tok_list[8][8192]
// First 32KB of tok_list region doubles as gate-record staging (512 x 64B);
// route loads ALL records before the scatter overwrites them.

// ---------------------------------------------------------------------------
// gate: 512 blocks x 256 thr; each block 16 tokens, each wave 4 tokens.
// Per token: 8 lane-groups x 8 lanes; group g computes expert g. No atomics.
// ---------------------------------------------------------------------------
__global__ __launch_bounds__(256) void gate_kernel(
    const float* __restrict__ x, const float* __restrict__ Wg,
    const float* __restrict__ bg, u32* __restrict__ stage)
{
    __shared__ int   am_s[16];
    __shared__ float mg_s[4][NE];

    const int tid  = threadIdx.x;
    const int wave = tid >> 6;
    const int lane = tid & 63;
    const int g    = lane >> 3;
    const int sub  = lane & 7;

    const float* wr = Wg + g * DIN + 4 * sub;

    float bgl[NE];
    #pragma unroll
    for (int e = 0; e < NE; ++e) bgl[e] = bg[e];

    float mgacc = 0.f;

    #pragma unroll 1
    for (int it = 0; it < 4; ++it) {
        const int t = blockIdx.x * 16 + wave * 4 + it;
        const float* xr = x + (size_t)t * DIN + 4 * sub;

        float acc0 = 0.f, acc1 = 0.f, acc2 = 0.f, acc3 = 0.f;
        #pragma unroll
        for (int j = 0; j < 8; ++j) {
            const int k = j * 128;
            f32x4 x0 = *(const f32x4*)(xr + k);
            f32x4 w0 = *(const f32x4*)(wr + k);
            f32x4 x1 = *(const f32x4*)(xr + k + 32);
            f32x4 w1 = *(const f32x4*)(wr + k + 32);
            f32x4 x2 = *(const f32x4*)(xr + k + 64);
            f32x4 w2 = *(const f32x4*)(wr + k + 64);
            f32x4 x3 = *(const f32x4*)(xr + k + 96);
            f32x4 w3 = *(const f32x4*)(wr + k + 96);
            #pragma unroll
            for (int q = 0; q < 4; ++q) {
                acc0 = fmaf(w0[q], x0[q], acc0);
                acc1 = fmaf(w1[q], x1[q], acc1);
                acc2 = fmaf(w2[q], x2[q], acc2);
                acc3 = fmaf(w3[q], x3[q], acc3);
            }
        }
        float acc = (acc0 + acc1) + (acc2 + acc3);

        acc += __shfl_xor(acc, 1, 64);
        acc += __shfl_xor(acc, 2, 64);
        acc += __shfl_xor(acc, 4, 64);

        float logit[NE];
        #pragma unroll
        for (int e = 0; e < NE; ++e)
            logit[e] = __shfl(acc, e * 8, 64) + bgl[e];

        float m = logit[0]; int am = 0;
        #pragma unroll
        for (int e = 1; e < NE; ++e) if (logit[e] > m) { m = logit[e]; am = e; }

        float p[NE], s = 0.f;
        #pragma unroll
        for (int e = 0; e < NE; ++e) { p[e] = __expf(logit[e] - m); s += p[e]; }
        const float inv = 1.f / s;

        float psel = p[0];
        #pragma unroll
        for (int e = 1; e < NE; ++e) psel = (lane == e) ? p[e] : psel;
        if (lane < NE) mgacc += psel * inv;

        if (lane == 0) am_s[wave * 4 + it] = am;
    }

    if (lane < NE) mg_s[wave][lane] = mgacc;
    __syncthreads();

    u32* rec = stage + (size_t)blockIdx.x * 16;
    if (tid == 0) {
        u64 pack = 0;
        #pragma unroll
        for (int i = 0; i < 16; ++i) pack |= (u64)am_s[i] << (4 * i);
        *(u64*)rec = pack;
    }
    if (tid < NE) {
        float s = mg_s[0][tid] + mg_s[1][tid] + mg_s[2][tid] + mg_s[3][tid];
        rec[2 + tid] = __float_as_uint(s);
    }
}

// ---------------------------------------------------------------------------
// route: 1 block x 512 threads. Thread i owns gate-block i (16 tokens).
// Count -> per-expert exclusive scan over blocks -> scatter -> counts/aux.
// ---------------------------------------------------------------------------
__global__ __launch_bounds__(512) void route_kernel(
    const u32* __restrict__ stage, int* __restrict__ counts,
    int* __restrict__ tok_list, float* __restrict__ out)
{
    __shared__ float mgl[512][NE];
    __shared__ int   c[512][9];
    __shared__ float tot_s[NE];

    const int tid  = threadIdx.x;
    const int wave = tid >> 6;
    const int lane = tid & 63;

    const u64 pack = *(const u64*)(stage + (size_t)tid * 16);
    #pragma unroll
    for (int e = 0; e < NE; ++e)
        mgl[tid][e] = __uint_as_float(stage[tid * 16 + 2 + e]);

    #pragma unroll
    for (int e = 0; e < 9; ++e) c[tid][e] = 0;

    #pragma unroll
    for (int it = 0; it < 16; ++it) {
        int e3 = (int)((pack >> (4 * it)) & 7);
        c[tid][e3]++;
    }
    __syncthreads();

    {
        const int e = wave;
        int carry = 0;
        #pragma unroll 1
        for (int ch = 0; ch < 8; ++ch) {
            int v = c[ch * 64 + lane][e];
            int incl = v;
            #pragma unroll
            for (int off = 1; off < 64; off <<= 1) {
                int n = __shfl_up(incl, off, 64);
                if (lane >= off) incl += n;
            }
            c[ch * 64 + lane][e] = incl - v + carry;
            carry += __shfl(incl, 63, 64);
        }
        if (lane == 0) counts[e] = carry;
    }
    __syncthreads();

    #pragma unroll
    for (int it = 0; it < 16; ++it) {
        int e3 = (int)((pack >> (4 * it)) & 7);
        int pos = c[tid][e3]++;
        tok_list[e3 * NTOK + pos] = tid * 16 + it;
    }

    {
        const int e = wave;
        float s = 0.f;
        #pragma unroll
        for (int ch = 0; ch < 8; ++ch) s += mgl[ch * 64 + lane][e];
        #pragma unroll
        for (int off = 32; off > 0; off >>= 1) s += __shfl_xor(s, off, 64);
        if (lane == 0) tot_s[e] = s;
    }
    __syncthreads();
    if (tid == 0) {
        float s = 0.f;
        #pragma unroll
        for (int e = 0; e < NE; ++e) {
            float m = tot_s[e] * (8.0f / 8192.0f);
            s += m * m;
        }
        out[(size_t)NTOK * DOUT] = s * 0.125f;
    }
}

// ---------------------------------------------------------------------------
// grouped GEMM v12: 64x128 tile, BK=64, 4 waves each 64x32, K-SPLIT x2.
// blockIdx.y = m*2 + kb; block kb covers K in [kb*512, kb*512+512).
// LDS: bf16 sA[64][64] (8KB) + sB[128][64] (16KB), single-buffered,
// XOR-swizzled chunks (cx = ch ^ (row&7)) -- verified 0 bank conflicts.
// Epilogue: unsafeAtomicAdd (HW global_atomic_add_f32); kb==0 adds bias.
// Grid dim3(8 n, 256 m*kb, 8 e): ~2048 live blocks = 8/CU.
// ---------------------------------------------------------------------------
__global__ __launch_bounds__(256) void moe_gemm(
    const float* __restrict__ x, const float* __restrict__ We,
    const float* __restrict__ be, const int* __restrict__ counts,
    const int* __restrict__ tok_list, float* __restrict__ out)
{
    const int e   = blockIdx.z;
    const int cnt = counts[e];
    const int m0  = (blockIdx.y >> 1) * 64;
    const int kb  = blockIdx.y & 1;
    if (m0 >= cnt) return;
    const int n0  = blockIdx.x * 128;

    __shared__ u16 sA[64 * 64];    // 8 KB
    __shared__ u16 sB[128 * 64];   // 16 KB
    __shared__ int toks[64];

    const int tid = threadIdx.x;
    if (tid < 64) {
        int gr = m0 + tid;
        toks[tid] = (gr < cnt) ? tok_list[e * NTOK + gr] : tok_list[e * NTOK];
    }
    __syncthreads();

    const int lane = tid & 63;
    const int wave = tid >> 6;
    const int wn   = wave * 32;
    const int lrow = lane & 15;
    const int quad = lane >> 4;
    const int l7   = lrow & 7;

    f32x4 acc[4][2];
    #pragma unroll
    for (int i = 0; i < 4; ++i)
        #pragma unroll
        for (int j = 0; j < 2; ++j) acc[i][j] = (f32x4){0.f, 0.f, 0.f, 0.f};

    const int srow = tid >> 3;
    const int ch   = tid & 7;
    const int cx   = ch ^ (srow & 7);

    const float* aS[2];
    const float* bS[4];
    #pragma unroll
    for (int s = 0; s < 2; ++s)
        aS[s] = x + (size_t)toks[srow + 32 * s] * DIN + ch * 8;
    #pragma unroll
    for (int s = 0; s < 4; ++s)
        bS[s] = We + ((size_t)e << 20) + ((size_t)(n0 + srow + 32 * s) << 10) + ch * 8;

    f32x4 ar[2][2], br[4][2];

    #define LOADR(k0)                                            \
        do {                                                     \
            _Pragma("unroll")                                    \
            for (int s = 0; s < 2; ++s) {                        \
                ar[s][0] = *(const f32x4*)(aS[s] + (k0));        \
                ar[s][1] = *(const f32x4*)(aS[s] + (k0) + 4);    \
            }                                                    \
            _Pragma("unroll")                                    \
            for (int s = 0; s < 4; ++s) {                        \
                br[s][0] = *(const f32x4*)(bS[s] + (k0));        \
                br[s][1] = *(const f32x4*)(bS[s] + (k0) + 4);    \
            }                                                    \
        } while (0)

    #define STOREW()                                                     \
        do {                                                             \
            _Pragma("unroll")                                            \
            for (int s = 0; s < 2; ++s) {                                \
                union { u16 h[8]; uint4 u; } ua;                         \
                _Pragma("unroll")                                        \
                for (int q = 0; q < 4; ++q) {                            \
                    ua.h[q]     = f2bf(ar[s][0][q]);                     \
                    ua.h[4 + q] = f2bf(ar[s][1][q]);                     \
                }                                                        \
                *(uint4*)&sA[(srow + 32 * s) * 64 + cx * 8] = ua.u;      \
            }                                                            \
            _Pragma("unroll")                                            \
            for (int s = 0; s < 4; ++s) {                                \
                union { u16 h[8]; uint4 u; } ub;                         \
                _Pragma("unroll")                                        \
                for (int q = 0; q < 4; ++q) {                            \
                    ub.h[q]     = f2bf(br[s][0][q]);                     \
                    ub.h[4 + q] = f2bf(br[s][1][q]);                     \
                }                                                        \
                *(uint4*)&sB[(srow + 32 * s) * 64 + cx * 8] = ub.u;      \
            }                                                            \
        } while (0)

    #define COMPUTE()                                                         \
        do {                                                                  \
            bf16x8 af[2][4], bv[2][2];                                        \
            _Pragma("unroll")                                                 \
            for (int ks = 0; ks < 2; ++ks) {                                  \
                const int so = ((ks * 4 + quad) ^ l7) * 8;                    \
                _Pragma("unroll")                                             \
                for (int i = 0; i < 4; ++i)                                   \
                    af[ks][i] = *(const bf16x8*)&sA[(i * 16 + lrow) * 64 + so]; \
                _Pragma("unroll")                                             \
                for (int j = 0; j < 2; ++j)                                   \
                    bv[ks][j] = *(const bf16x8*)&sB[(wn + j * 16 + lrow) * 64 + so]; \
            }                                                                 \
            _Pragma("unroll")                                                 \
            for (int ks = 0; ks < 2; ++ks)                                    \
                _Pragma("unroll")                                             \
                for (int i = 0; i < 4; ++i)                                   \
                    _Pragma("unroll")                                         \
                    for (int j = 0; j < 2; ++j)                               \
                        acc[i][j] = __builtin_amdgcn_mfma_f32_16x16x32_bf16(  \
                            af[ks][i], bv[ks][j], acc[i][j], 0, 0, 0);        \
        } while (0)

    const int kbeg = kb * 512;
    LOADR(kbeg);
    #pragma unroll 1
    for (int k0 = kbeg; k0 < kbeg + 512; k0 += 64) {
        __syncthreads();
        STOREW();
        if (k0 + 64 < kbeg + 512) LOADR(k0 + 64);
        __syncthreads();
        COMPUTE();
    }

    #undef LOADR
    #undef STOREW
    #undef COMPUTE

    // epilogue: HW fp32 atomics; kb==0 contributes the bias
    #pragma unroll
    for (int j = 0; j < 2; ++j) {
        const int col = n0 + wn + j * 16 + lrow;
        const float bev = (kb == 0) ? be[e * DOUT + col] : 0.f;
        #pragma unroll
        for (int i = 0; i < 4; ++i) {
            #pragma unroll
            for (int r = 0; r < 4; ++r) {
                const int rl = i * 16 + quad * 4 + r;
                if (m0 + rl < cnt) {
                    const int tok = toks[rl];
                    unsafeAtomicAdd(&out[((size_t)tok << 10) + col],
                                    acc[i][j][r] + bev);
                }
            }
        }
    }
}

extern "C" void kernel_launch(void* const* d_in, const int* in_sizes, int n_in,
                              void* d_out, int out_size, void* d_ws, size_t ws_size,
                              hipStream_t stream) {
    const float* x  = (const float*)d_in[0];
    const float* We = (const float*)d_in[1];
    const float* be = (const float*)d_in[2];
    const float* Wg = (const float*)d_in[3];
    const float* bg = (const float*)d_in[4];
    float* out = (float*)d_out;

    int* counts   = (int*)d_ws;
    int* tok_list = (int*)((char*)d_ws + 256);
    u32* stage    = (u32*)((char*)d_ws + 256);

    gate_kernel<<<512, 256, 0, stream>>>(x, Wg, bg, stage);
    route_kernel<<<1, 512, 0, stream>>>(stage, counts, tok_list, out);
    moe_gemm<<<dim3(8, 256, 8), 256, 0, stream>>>(x, We, be, counts, tok_list, out);
}